// Round 4
// baseline (2939.132 us; speedup 1.0000x reference)
//
#include <hip/hip_runtime.h>

typedef _Float16 f16;
typedef _Float16 f16x8 __attribute__((ext_vector_type(8)));
typedef float f32x16 __attribute__((ext_vector_type(16)));
typedef unsigned short u16;
typedef unsigned int u32;

#define NSAMP 131072
#define HID 512
#define NW 4               // waves per block (1 per SIMD, max-reg mode)
#define ST 4               // sample-tiles (of 32) per wave == per block
#define BSAMP 128          // samples per block

#define ACT_BYTES (BSAMP * 1024)                   // [samp][feat fp16], 128KB
#define STATS_OFF ACT_BYTES
#define LDS_TOTAL (ACT_BYTES + NW * BSAMP * 8)     // + 4KB partial LN stats

// activation width after layer l (l = 0..6) for factor f
__host__ __device__ constexpr int wact(int f, int l) {
    if (f == 0) return 256;
    if (f == 2) return 512;
    return (l & 1) ? 256 : 512;   // factor 1: 512,256,512,...
}
// weight tiles (1KB = 32x16 fp16 A-fragment tile) per (factor, layer 0..7)
__host__ __device__ constexpr int seg_tiles(int f, int l) {
    if (l == 0) return wact(f, 0) / 32;                   // KT=1 (K: 6 padded to 16)
    if (l == 7) return wact(f, 6) / 16;                   // FT=1 (rows: 3 padded to 32)
    return (wact(f, l) / 32) * (wact(f, l - 1) / 16);     // FT*KT
}
__host__ __device__ constexpr int seg_off(int f, int l) {
    int o = 0;
    for (int ff = 0; ff < 3; ++ff)
        for (int ll = 0; ll < 8; ++ll) {
            if (ff == f && ll == l) return o;
            o += seg_tiles(ff, ll);
        }
    return o;
}
constexpr int TOTAL_TILES = seg_off(2, 7) + seg_tiles(2, 7);   // 5496 tiles -> 5.5MB in d_ws

// ---------------- prep: convert + tile all weights to fp16 A-fragment layout ----------------
// tile t = kt*FT + ft; element e = lane*8 + j holds W[ft*32 + (lane&31)][kt*16 + (lane>>5)*8 + j]
__global__ __launch_bounds__(256) void prep_kernel(const float* __restrict__ W_in,
                                                   const float* __restrict__ Ws,
                                                   const float* __restrict__ W_out,
                                                   u16* __restrict__ wt) {
    int b = blockIdx.x;
    int f = 0, l = 0, start = 0;
    for (int s = 0; s < 24; ++s) {
        int ff = s >> 3, ll = s & 7;
        int t = seg_tiles(ff, ll);
        if (b < start + t) { f = ff; l = ll; break; }
        start += t;
    }
    int lt = b - start;
    int FT = (l == 7) ? 1 : wact(f, l) / 32;
    int sh = (FT == 16) ? 4 : (FT == 8) ? 3 : 0;
    int kt = lt >> sh;
    int ft = lt & (FT - 1);
    const float* src; int stride, vr, vc;
    if (l == 0)      { src = W_in;                     stride = 6;   vr = 512; vc = 6;   }
    else if (l == 7) { src = W_out;                    stride = HID; vr = 3;   vc = HID; }
    else             { src = Ws + (l - 1) * HID * HID; stride = HID; vr = HID; vc = HID; }
    u16* dst = wt + (size_t)b * 512;
    #pragma unroll
    for (int t = 0; t < 2; ++t) {
        int e = threadIdx.x * 2 + t;
        int lane = e >> 3, j = e & 7;
        int row = ft * 32 + (lane & 31);
        int col = kt * 16 + (lane >> 5) * 8 + j;
        float v = (row < vr && col < vc) ? src[row * stride + col] : 0.0f;
        dst[e] = __builtin_bit_cast(u16, (f16)v);
    }
}

// ---------------- main fused kernel helpers ----------------
__device__ __forceinline__ f32x16 zero16() {
    f32x16 z = {0.f,0.f,0.f,0.f,0.f,0.f,0.f,0.f,0.f,0.f,0.f,0.f,0.f,0.f,0.f,0.f};
    return z;
}
__device__ __forceinline__ f16x8 bc(const uint4 v) { return __builtin_bit_cast(f16x8, v); }

// In-register epilogue, r2-exact numerics:
//   v = acc + bias (fp32); stats from v; x = fp16(v); xn = (float(x)-mean)*rstd;
//   y = relu(lw*xn + lb); act <- fp16(y)
// D layout (32x32): col(sample) = lane&31, row(feat-local) = (r&3) + 8*(r>>2) + 4*h
// act byte addr for [samp][featbyte]: samp*1024 + (featbyte ^ ((samp&15)<<4))
template<int FW, int DOUT>
__device__ __forceinline__ void epilogue(f32x16 (&acc)[FW][ST],
                                         const float* __restrict__ bias,
                                         const float* __restrict__ lw,
                                         const float* __restrict__ lb,
                                         char* act, char* stats,
                                         int ft0, int w, int sl, int h, int swz) {
    constexpr float invD = 1.0f / DOUT;
    float s[ST] = {0.f,0.f,0.f,0.f}, ss[ST] = {0.f,0.f,0.f,0.f};
    #pragma unroll
    for (int j = 0; j < FW; ++j) {
        #pragma unroll
        for (int q = 0; q < 4; ++q) {
            float4 bv = *reinterpret_cast<const float4*>(bias + (ft0 + j) * 32 + q * 8 + h * 4);
            #pragma unroll
            for (int st = 0; st < ST; ++st) {
                #pragma unroll
                for (int r = 0; r < 4; ++r) {
                    float v = acc[j][st][q * 4 + r] + (&bv.x)[r];
                    acc[j][st][q * 4 + r] = v;
                    s[st] += v; ss[st] += v * v;
                }
            }
        }
    }
    #pragma unroll
    for (int st = 0; st < ST; ++st) {
        s[st]  += __shfl_xor(s[st], 32);
        ss[st] += __shfl_xor(ss[st], 32);
    }
    __syncthreads();   // paranoia barrier0: all waves' act B-reads complete
    if (h == 0) {
        #pragma unroll
        for (int st = 0; st < ST; ++st)
            *reinterpret_cast<float2*>(stats + ((size_t)w * BSAMP + st * 32 + sl) * 8) =
                make_float2(s[st], ss[st]);
    }
    __syncthreads();   // barrier1: stats visible; act writes gated behind this
    float mean_[ST], rstd_[ST];
    #pragma unroll
    for (int st = 0; st < ST; ++st) {
        float S = 0.f, SS = 0.f;
        #pragma unroll
        for (int ww = 0; ww < NW; ++ww) {
            float2 p = *reinterpret_cast<const float2*>(stats + ((size_t)ww * BSAMP + st * 32 + sl) * 8);
            S += p.x; SS += p.y;
        }
        float mean = S * invD;
        float var  = SS * invD - mean * mean;
        mean_[st] = mean;
        rstd_[st] = 1.0f / sqrtf(var + 1e-5f);
    }
    #pragma unroll
    for (int j = 0; j < FW; ++j) {
        #pragma unroll
        for (int q = 0; q < 4; ++q) {
            float4 wv  = *reinterpret_cast<const float4*>(lw + (ft0 + j) * 32 + q * 8 + h * 4);
            float4 lbv = *reinterpret_cast<const float4*>(lb + (ft0 + j) * 32 + q * 8 + h * 4);
            #pragma unroll
            for (int st = 0; st < ST; ++st) {
                float o[4];
                #pragma unroll
                for (int r = 0; r < 4; ++r) {
                    f16 x16 = (f16)acc[j][st][q * 4 + r];       // r2-exact: normalize quantized value
                    float xn = (((float)x16) - mean_[st]) * rstd_[st];
                    o[r] = fmaxf((&wv.x)[r] * xn + (&lbv.x)[r], 0.f);
                }
                u32 p0 = (u32)__builtin_bit_cast(u16, (f16)o[0]) | ((u32)__builtin_bit_cast(u16, (f16)o[1]) << 16);
                u32 p1 = (u32)__builtin_bit_cast(u16, (f16)o[2]) | ((u32)__builtin_bit_cast(u16, (f16)o[3]) << 16);
                int byte = (st * 32 + sl) * 1024 + (((ft0 + j) * 64 + q * 16 + h * 8) ^ swz);
                *reinterpret_cast<uint2*>(act + byte) = make_uint2(p0, p1);
            }
        }
    }
    __syncthreads();   // barrier2: act ready for next layer
}

// hidden layer: A from global (2-deep pipeline, clamped in-bounds), B from swizzled LDS
template<int DIN, int DOUT>
__device__ __forceinline__ void hidden(const u16* __restrict__ seg,
                                       const float* __restrict__ bias,
                                       const float* __restrict__ lw,
                                       const float* __restrict__ lb,
                                       char* act, char* stats,
                                       int w, int lane, int h, int sl, int swz) {
    constexpr int KT = DIN / 16, FTT = DOUT / 32, FW = FTT / NW;
    constexpr int AST = FTT * 1024;
    const int ft0 = w * FW;
    f32x16 acc[FW][ST];
    #pragma unroll
    for (int j = 0; j < FW; ++j)
        #pragma unroll
        for (int st = 0; st < ST; ++st) acc[j][st] = zero16();
    const char* abase = (const char*)seg + (size_t)ft0 * 1024 + lane * 16;
    uint4 cur[FW], nxt[FW];
    #pragma unroll
    for (int j = 0; j < FW; ++j) cur[j] = *reinterpret_cast<const uint4*>(abase + j * 1024);
    #pragma unroll
    for (int j = 0; j < FW; ++j) nxt[j] = *reinterpret_cast<const uint4*>(abase + AST + j * 1024);
    #pragma unroll 2
    for (int kt = 0; kt < KT; ++kt) {
        uint4 pf[FW];
        const int ktp = (kt + 2 < KT) ? (kt + 2) : kt;   // clamp: in-bounds, defined values
        #pragma unroll
        for (int j = 0; j < FW; ++j)
            pf[j] = *reinterpret_cast<const uint4*>(abase + (size_t)ktp * AST + j * 1024);
        f16x8 B[ST];
        #pragma unroll
        for (int st = 0; st < ST; ++st)
            B[st] = bc(*reinterpret_cast<const uint4*>(act + (st * 32 + sl) * 1024 + ((kt * 32 + h * 16) ^ swz)));
        #pragma unroll
        for (int j = 0; j < FW; ++j) {
            f16x8 A = bc(cur[j]);
            #pragma unroll
            for (int st = 0; st < ST; ++st)
                acc[j][st] = __builtin_amdgcn_mfma_f32_32x32x16_f16(A, B[st], acc[j][st], 0, 0, 0);
        }
        #pragma unroll
        for (int j = 0; j < FW; ++j) { cur[j] = nxt[j]; nxt[j] = pf[j]; }
    }
    epilogue<FW, DOUT>(acc, bias, lw, lb, act, stats, ft0, w, sl, h, swz);
}

// input layer: K=16 (6 real + pad), B from registers (no LDS reads)
template<int DOUT>
__device__ __forceinline__ void layer_in(const u16* __restrict__ seg,
                                         const float* __restrict__ bias,
                                         const float* __restrict__ lw,
                                         const float* __restrict__ lb,
                                         char* act, char* stats, const f16x8 (&ib)[ST],
                                         int w, int lane, int h, int sl, int swz) {
    constexpr int FTT = DOUT / 32, FW = FTT / NW;
    const int ft0 = w * FW;
    f32x16 acc[FW][ST];
    #pragma unroll
    for (int j = 0; j < FW; ++j)
        #pragma unroll
        for (int st = 0; st < ST; ++st) acc[j][st] = zero16();
    const char* abase = (const char*)seg + (size_t)ft0 * 1024 + lane * 16;
    #pragma unroll
    for (int j = 0; j < FW; ++j) {
        f16x8 A = bc(*reinterpret_cast<const uint4*>(abase + j * 1024));
        #pragma unroll
        for (int st = 0; st < ST; ++st)
            acc[j][st] = __builtin_amdgcn_mfma_f32_32x32x16_f16(A, ib[st], acc[j][st], 0, 0, 0);
    }
    epilogue<FW, DOUT>(acc, bias, lw, lb, act, stats, ft0, w, sl, h, swz);
}

// output layer: 3 features; wave w handles sample-tile w; trailing barrier
template<int DIN>
__device__ __forceinline__ void layer_out(const u16* __restrict__ seg,
                                          const float* __restrict__ b_out,
                                          const char* act, float* __restrict__ out,
                                          int F, int samp0, int w, int lane, int h, int sl, int swz) {
    constexpr int KT = DIN / 16;
    f32x16 acc = zero16();
    const char* abase = (const char*)seg + lane * 16;
    const int samp = w * 32 + sl;
    #pragma unroll
    for (int kt = 0; kt < KT; ++kt) {
        f16x8 A = bc(*reinterpret_cast<const uint4*>(abase + kt * 1024));
        f16x8 B = bc(*reinterpret_cast<const uint4*>(act + samp * 1024 + ((kt * 32 + h * 16) ^ swz)));
        acc = __builtin_amdgcn_mfma_f32_32x32x16_f16(A, B, acc, 0, 0, 0);
    }
    if (h == 0) {
        float* o = out + (size_t)(samp0 + samp) * 9 + F * 3;
        o[0] = acc[0] + b_out[0];
        o[1] = acc[1] + b_out[1];
        o[2] = acc[2] + b_out[2];
    }
    __syncthreads();   // paranoia: separate act reads from next factor's activity
}

template<int F>
__device__ __forceinline__ void run_factor(const float* __restrict__ b_in,
                                           const float* __restrict__ bs,
                                           const float* __restrict__ lnw,
                                           const float* __restrict__ lnb,
                                           const float* __restrict__ b_out,
                                           const u16* __restrict__ wt,
                                           float* __restrict__ out,
                                           char* act, char* stats, const f16x8 (&ib)[ST],
                                           int samp0, int w, int lane, int h, int sl, int swz) {
    layer_in<wact(F,0)>(wt + (size_t)seg_off(F,0) * 512, b_in, lnw, lnb, act, stats, ib, w, lane, h, sl, swz);
    hidden<wact(F,0), wact(F,1)>(wt + (size_t)seg_off(F,1) * 512, bs + 0*HID, lnw + 1*HID, lnb + 1*HID, act, stats, w, lane, h, sl, swz);
    hidden<wact(F,1), wact(F,2)>(wt + (size_t)seg_off(F,2) * 512, bs + 1*HID, lnw + 2*HID, lnb + 2*HID, act, stats, w, lane, h, sl, swz);
    hidden<wact(F,2), wact(F,3)>(wt + (size_t)seg_off(F,3) * 512, bs + 2*HID, lnw + 3*HID, lnb + 3*HID, act, stats, w, lane, h, sl, swz);
    hidden<wact(F,3), wact(F,4)>(wt + (size_t)seg_off(F,4) * 512, bs + 3*HID, lnw + 4*HID, lnb + 4*HID, act, stats, w, lane, h, sl, swz);
    hidden<wact(F,4), wact(F,5)>(wt + (size_t)seg_off(F,5) * 512, bs + 4*HID, lnw + 5*HID, lnb + 5*HID, act, stats, w, lane, h, sl, swz);
    hidden<wact(F,5), wact(F,6)>(wt + (size_t)seg_off(F,6) * 512, bs + 5*HID, lnw + 6*HID, lnb + 6*HID, act, stats, w, lane, h, sl, swz);
    layer_out<wact(F,6)>(wt + (size_t)seg_off(F,7) * 512, b_out, act, out, F, samp0, w, lane, h, sl, swz);
}

__global__ __launch_bounds__(NW * 64, 1) void mipnet_kernel(
        const float* __restrict__ inp, const float* __restrict__ b_in,
        const float* __restrict__ bs, const float* __restrict__ lnw,
        const float* __restrict__ lnb, const float* __restrict__ b_out,
        const u16* __restrict__ wt, float* __restrict__ out) {
    extern __shared__ char lds[];
    char* act   = lds;
    char* stats = lds + STATS_OFF;
    const int tid  = threadIdx.x;
    const int w    = tid >> 6;
    const int lane = tid & 63;
    const int h    = lane >> 5;
    const int sl   = lane & 31;
    const int swz  = (sl & 15) << 4;     // r2-exact swizzle (bits 4-7)
    const int samp0 = blockIdx.x * BSAMP;

    // input B-fragments, built once, reused by all 3 factors (K = 6 padded to 16)
    f16x8 ib[ST];
    #pragma unroll
    for (int st = 0; st < ST; ++st) {
        f16x8 B = {(f16)0.f,(f16)0.f,(f16)0.f,(f16)0.f,(f16)0.f,(f16)0.f,(f16)0.f,(f16)0.f};
        if (h == 0) {
            const float* p = inp + (size_t)(samp0 + st * 32 + sl) * 6;
            float2 v0 = *reinterpret_cast<const float2*>(p + 0);
            float2 v1 = *reinterpret_cast<const float2*>(p + 2);
            float2 v2 = *reinterpret_cast<const float2*>(p + 4);
            B[0] = (f16)v0.x; B[1] = (f16)v0.y;
            B[2] = (f16)v1.x; B[3] = (f16)v1.y;
            B[4] = (f16)v2.x; B[5] = (f16)v2.y;
        }
        ib[st] = B;
    }
    run_factor<0>(b_in, bs, lnw, lnb, b_out, wt, out, act, stats, ib, samp0, w, lane, h, sl, swz);
    run_factor<1>(b_in, bs, lnw, lnb, b_out, wt, out, act, stats, ib, samp0, w, lane, h, sl, swz);
    run_factor<2>(b_in, bs, lnw, lnb, b_out, wt, out, act, stats, ib, samp0, w, lane, h, sl, swz);
}

extern "C" void kernel_launch(void* const* d_in, const int* in_sizes, int n_in,
                              void* d_out, int out_size, void* d_ws, size_t ws_size,
                              hipStream_t stream) {
    (void)in_sizes; (void)n_in; (void)out_size; (void)ws_size;
    const float* inputs = (const float*)d_in[0];
    const float* W_in   = (const float*)d_in[1];
    const float* b_in   = (const float*)d_in[2];
    const float* Ws     = (const float*)d_in[3];
    const float* bs     = (const float*)d_in[4];
    const float* lnw    = (const float*)d_in[5];
    const float* lnb    = (const float*)d_in[6];
    const float* W_out  = (const float*)d_in[7];
    const float* b_out  = (const float*)d_in[8];
    u16* wt = (u16*)d_ws;   // TOTAL_TILES*1024 = ~5.5MB of scratch

    hipFuncSetAttribute(reinterpret_cast<const void*>(mipnet_kernel),
                        hipFuncAttributeMaxDynamicSharedMemorySize, LDS_TOTAL);

    prep_kernel<<<TOTAL_TILES, 256, 0, stream>>>(W_in, Ws, W_out, wt);
    mipnet_kernel<<<NSAMP / BSAMP, NW * 64, LDS_TOTAL, stream>>>(
        inputs, b_in, bs, lnw, lnb, b_out, wt, (float*)d_out);
}

// Round 5
// 1355.693 us; speedup vs baseline: 2.1680x; 2.1680x over previous
//
#include <hip/hip_runtime.h>

typedef _Float16 f16;
typedef _Float16 f16x8 __attribute__((ext_vector_type(8)));
typedef float f32x16 __attribute__((ext_vector_type(16)));
typedef unsigned short u16;
typedef unsigned int u32;

#define NSAMP 131072
#define HID 512
#define NW 8               // waves per block (2 per SIMD)
#define ST 4               // sample-tiles (of 32) per block
#define BSAMP 128          // samples per block

#define ACT_BYTES (BSAMP * 1024)                   // [samp][feat fp16], 128KB
#define STATS_OFF ACT_BYTES
#define LDS_TOTAL (ACT_BYTES + NW * BSAMP * 8)     // + 8KB partial LN stats = 136KB

// activation width after layer l (l = 0..6) for factor f
__host__ __device__ constexpr int wact(int f, int l) {
    if (f == 0) return 256;
    if (f == 2) return 512;
    return (l & 1) ? 256 : 512;   // factor 1: 512,256,512,...
}
// weight tiles (1KB = 32x16 fp16 A-fragment tile) per (factor, layer 0..7)
__host__ __device__ constexpr int seg_tiles(int f, int l) {
    if (l == 0) return wact(f, 0) / 32;                   // KT=1 (K: 6 padded to 16)
    if (l == 7) return wact(f, 6) / 16;                   // FT=1 (rows: 3 padded to 32)
    return (wact(f, l) / 32) * (wact(f, l - 1) / 16);     // FT*KT
}
__host__ __device__ constexpr int seg_off(int f, int l) {
    int o = 0;
    for (int ff = 0; ff < 3; ++ff)
        for (int ll = 0; ll < 8; ++ll) {
            if (ff == f && ll == l) return o;
            o += seg_tiles(ff, ll);
        }
    return o;
}
constexpr int TOTAL_TILES = seg_off(2, 7) + seg_tiles(2, 7);   // 5496 tiles -> 5.5MB in d_ws

// ---------------- prep: convert + tile all weights to fp16 A-fragment layout ----------------
// tile t = kt*FT + ft; element e = lane*8 + j holds W[ft*32 + (lane&31)][kt*16 + (lane>>5)*8 + j]
__global__ __launch_bounds__(256) void prep_kernel(const float* __restrict__ W_in,
                                                   const float* __restrict__ Ws,
                                                   const float* __restrict__ W_out,
                                                   u16* __restrict__ wt) {
    int b = blockIdx.x;
    int f = 0, l = 0, start = 0;
    for (int s = 0; s < 24; ++s) {
        int ff = s >> 3, ll = s & 7;
        int t = seg_tiles(ff, ll);
        if (b < start + t) { f = ff; l = ll; break; }
        start += t;
    }
    int lt = b - start;
    int FT = (l == 7) ? 1 : wact(f, l) / 32;
    int sh = (FT == 16) ? 4 : (FT == 8) ? 3 : 0;
    int kt = lt >> sh;
    int ft = lt & (FT - 1);
    const float* src; int stride, vr, vc;
    if (l == 0)      { src = W_in;                     stride = 6;   vr = 512; vc = 6;   }
    else if (l == 7) { src = W_out;                    stride = HID; vr = 3;   vc = HID; }
    else             { src = Ws + (l - 1) * HID * HID; stride = HID; vr = HID; vc = HID; }
    u16* dst = wt + (size_t)b * 512;
    #pragma unroll
    for (int t = 0; t < 2; ++t) {
        int e = threadIdx.x * 2 + t;
        int lane = e >> 3, j = e & 7;
        int row = ft * 32 + (lane & 31);
        int col = kt * 16 + (lane >> 5) * 8 + j;
        float v = (row < vr && col < vc) ? src[row * stride + col] : 0.0f;
        dst[e] = __builtin_bit_cast(u16, (f16)v);
    }
}

// ---------------- main fused kernel helpers ----------------
__device__ __forceinline__ f32x16 zero16() {
    f32x16 z = {0.f,0.f,0.f,0.f,0.f,0.f,0.f,0.f,0.f,0.f,0.f,0.f,0.f,0.f,0.f,0.f};
    return z;
}
__device__ __forceinline__ f16x8 bc(const uint4 v) { return __builtin_bit_cast(f16x8, v); }

// In-register epilogue, r2-exact numerics:
//   v = acc + bias (fp32); stats from v; x = fp16(v); xn = (float(x)-mean)*rstd;
//   y = relu(lw*xn + lb); act <- fp16(y)
// D layout (32x32): col(sample) = lane&31, row(feat-local) = (r&3) + 8*(r>>2) + 4*h
// act byte addr for [samp][featbyte]: samp*1024 + (featbyte ^ ((samp&15)<<4))
// Barrier A (after stats write): orders all waves' act B-reads before act writes,
// and makes stats visible. Barrier B (after act writes): act ready for next layer.
template<int FW, int DOUT>
__device__ __forceinline__ void epilogue(f32x16 (&acc)[FW][ST],
                                         const float* __restrict__ bias,
                                         const float* __restrict__ lw,
                                         const float* __restrict__ lb,
                                         char* act, char* stats,
                                         int ft0, int w, int sl, int h, int swz) {
    constexpr float invD = 1.0f / DOUT;
    float s[ST] = {0.f,0.f,0.f,0.f}, ss[ST] = {0.f,0.f,0.f,0.f};
    #pragma unroll
    for (int j = 0; j < FW; ++j) {
        #pragma unroll
        for (int q = 0; q < 4; ++q) {
            float4 bv = *reinterpret_cast<const float4*>(bias + (ft0 + j) * 32 + q * 8 + h * 4);
            #pragma unroll
            for (int st = 0; st < ST; ++st) {
                #pragma unroll
                for (int r = 0; r < 4; ++r) {
                    float v = acc[j][st][q * 4 + r] + (&bv.x)[r];
                    acc[j][st][q * 4 + r] = v;
                    s[st] += v; ss[st] += v * v;
                }
            }
        }
    }
    #pragma unroll
    for (int st = 0; st < ST; ++st) {
        s[st]  += __shfl_xor(s[st], 32);
        ss[st] += __shfl_xor(ss[st], 32);
    }
    if (h == 0) {
        #pragma unroll
        for (int st = 0; st < ST; ++st)
            *reinterpret_cast<float2*>(stats + ((size_t)w * BSAMP + st * 32 + sl) * 8) =
                make_float2(s[st], ss[st]);
    }
    __syncthreads();   // barrier A: stats visible + all act B-reads complete
    float mean_[ST], rstd_[ST];
    #pragma unroll
    for (int st = 0; st < ST; ++st) {
        float S = 0.f, SS = 0.f;
        #pragma unroll
        for (int ww = 0; ww < NW; ++ww) {
            float2 p = *reinterpret_cast<const float2*>(stats + ((size_t)ww * BSAMP + st * 32 + sl) * 8);
            S += p.x; SS += p.y;
        }
        float mean = S * invD;
        float var  = SS * invD - mean * mean;
        mean_[st] = mean;
        rstd_[st] = 1.0f / sqrtf(var + 1e-5f);
    }
    #pragma unroll
    for (int j = 0; j < FW; ++j) {
        #pragma unroll
        for (int q = 0; q < 4; ++q) {
            float4 wv  = *reinterpret_cast<const float4*>(lw + (ft0 + j) * 32 + q * 8 + h * 4);
            float4 lbv = *reinterpret_cast<const float4*>(lb + (ft0 + j) * 32 + q * 8 + h * 4);
            #pragma unroll
            for (int st = 0; st < ST; ++st) {
                float o[4];
                #pragma unroll
                for (int r = 0; r < 4; ++r) {
                    f16 x16 = (f16)acc[j][st][q * 4 + r];       // r2-exact: normalize quantized value
                    float xn = (((float)x16) - mean_[st]) * rstd_[st];
                    o[r] = fmaxf((&wv.x)[r] * xn + (&lbv.x)[r], 0.f);
                }
                u32 p0 = (u32)__builtin_bit_cast(u16, (f16)o[0]) | ((u32)__builtin_bit_cast(u16, (f16)o[1]) << 16);
                u32 p1 = (u32)__builtin_bit_cast(u16, (f16)o[2]) | ((u32)__builtin_bit_cast(u16, (f16)o[3]) << 16);
                int byte = (st * 32 + sl) * 1024 + (((ft0 + j) * 64 + q * 16 + h * 8) ^ swz);
                *reinterpret_cast<uint2*>(act + byte) = make_uint2(p0, p1);
            }
        }
    }
    __syncthreads();   // barrier B: act ready for next layer
}

// hidden layer: A from global (2-deep pipeline, clamped in-bounds), B from swizzled LDS
template<int DIN, int DOUT>
__device__ __forceinline__ void hidden(const u16* __restrict__ seg,
                                       const float* __restrict__ bias,
                                       const float* __restrict__ lw,
                                       const float* __restrict__ lb,
                                       char* act, char* stats,
                                       int w, int lane, int h, int sl, int swz) {
    constexpr int KT = DIN / 16, FTT = DOUT / 32, FW = FTT / NW;
    constexpr int AST = FTT * 1024;
    const int ft0 = w * FW;
    f32x16 acc[FW][ST];
    #pragma unroll
    for (int j = 0; j < FW; ++j)
        #pragma unroll
        for (int st = 0; st < ST; ++st) acc[j][st] = zero16();
    const char* abase = (const char*)seg + (size_t)ft0 * 1024 + lane * 16;
    uint4 cur[FW], nxt[FW];
    #pragma unroll
    for (int j = 0; j < FW; ++j) cur[j] = *reinterpret_cast<const uint4*>(abase + j * 1024);
    #pragma unroll
    for (int j = 0; j < FW; ++j) nxt[j] = *reinterpret_cast<const uint4*>(abase + AST + j * 1024);
    #pragma unroll 2
    for (int kt = 0; kt < KT; ++kt) {
        uint4 pf[FW];
        const int ktp = (kt + 2 < KT) ? (kt + 2) : kt;   // clamp: in-bounds, defined values
        #pragma unroll
        for (int j = 0; j < FW; ++j)
            pf[j] = *reinterpret_cast<const uint4*>(abase + (size_t)ktp * AST + j * 1024);
        f16x8 B[ST];
        #pragma unroll
        for (int st = 0; st < ST; ++st)
            B[st] = bc(*reinterpret_cast<const uint4*>(act + (st * 32 + sl) * 1024 + ((kt * 32 + h * 16) ^ swz)));
        #pragma unroll
        for (int j = 0; j < FW; ++j) {
            f16x8 A = bc(cur[j]);
            #pragma unroll
            for (int st = 0; st < ST; ++st)
                acc[j][st] = __builtin_amdgcn_mfma_f32_32x32x16_f16(A, B[st], acc[j][st], 0, 0, 0);
        }
        #pragma unroll
        for (int j = 0; j < FW; ++j) { cur[j] = nxt[j]; nxt[j] = pf[j]; }
    }
    epilogue<FW, DOUT>(acc, bias, lw, lb, act, stats, ft0, w, sl, h, swz);
}

// input layer: K=16 (6 real + pad), B from registers (no LDS reads)
template<int DOUT>
__device__ __forceinline__ void layer_in(const u16* __restrict__ seg,
                                         const float* __restrict__ bias,
                                         const float* __restrict__ lw,
                                         const float* __restrict__ lb,
                                         char* act, char* stats, const f16x8 (&ib)[ST],
                                         int w, int lane, int h, int sl, int swz) {
    constexpr int FTT = DOUT / 32, FW = FTT / NW;
    const int ft0 = w * FW;
    f32x16 acc[FW][ST];
    #pragma unroll
    for (int j = 0; j < FW; ++j)
        #pragma unroll
        for (int st = 0; st < ST; ++st) acc[j][st] = zero16();
    const char* abase = (const char*)seg + (size_t)ft0 * 1024 + lane * 16;
    #pragma unroll
    for (int j = 0; j < FW; ++j) {
        f16x8 A = bc(*reinterpret_cast<const uint4*>(abase + j * 1024));
        #pragma unroll
        for (int st = 0; st < ST; ++st)
            acc[j][st] = __builtin_amdgcn_mfma_f32_32x32x16_f16(A, ib[st], acc[j][st], 0, 0, 0);
    }
    epilogue<FW, DOUT>(acc, bias, lw, lb, act, stats, ft0, w, sl, h, swz);
}

// output layer: 3 features; waves 0..3 each handle one sample-tile.
// No trailing barrier: the next layer_in's act writes are gated by its own barrier A,
// which each wave reaches only after finishing its layer_out reads (program order).
template<int DIN>
__device__ __forceinline__ void layer_out(const u16* __restrict__ seg,
                                          const float* __restrict__ b_out,
                                          const char* act, float* __restrict__ out,
                                          int F, int samp0, int w, int lane, int h, int sl, int swz) {
    if (w < ST) {
        constexpr int KT = DIN / 16;
        f32x16 acc = zero16();
        const char* abase = (const char*)seg + lane * 16;
        const int samp = w * 32 + sl;
        #pragma unroll
        for (int kt = 0; kt < KT; ++kt) {
            f16x8 A = bc(*reinterpret_cast<const uint4*>(abase + kt * 1024));
            f16x8 B = bc(*reinterpret_cast<const uint4*>(act + samp * 1024 + ((kt * 32 + h * 16) ^ swz)));
            acc = __builtin_amdgcn_mfma_f32_32x32x16_f16(A, B, acc, 0, 0, 0);
        }
        if (h == 0) {
            float* o = out + (size_t)(samp0 + samp) * 9 + F * 3;
            o[0] = acc[0] + b_out[0];
            o[1] = acc[1] + b_out[1];
            o[2] = acc[2] + b_out[2];
        }
    }
}

template<int F>
__device__ __forceinline__ void run_factor(const float* __restrict__ b_in,
                                           const float* __restrict__ bs,
                                           const float* __restrict__ lnw,
                                           const float* __restrict__ lnb,
                                           const float* __restrict__ b_out,
                                           const u16* __restrict__ wt,
                                           float* __restrict__ out,
                                           char* act, char* stats, const f16x8 (&ib)[ST],
                                           int samp0, int w, int lane, int h, int sl, int swz) {
    layer_in<wact(F,0)>(wt + (size_t)seg_off(F,0) * 512, b_in, lnw, lnb, act, stats, ib, w, lane, h, sl, swz);
    hidden<wact(F,0), wact(F,1)>(wt + (size_t)seg_off(F,1) * 512, bs + 0*HID, lnw + 1*HID, lnb + 1*HID, act, stats, w, lane, h, sl, swz);
    hidden<wact(F,1), wact(F,2)>(wt + (size_t)seg_off(F,2) * 512, bs + 1*HID, lnw + 2*HID, lnb + 2*HID, act, stats, w, lane, h, sl, swz);
    hidden<wact(F,2), wact(F,3)>(wt + (size_t)seg_off(F,3) * 512, bs + 2*HID, lnw + 3*HID, lnb + 3*HID, act, stats, w, lane, h, sl, swz);
    hidden<wact(F,3), wact(F,4)>(wt + (size_t)seg_off(F,4) * 512, bs + 3*HID, lnw + 4*HID, lnb + 4*HID, act, stats, w, lane, h, sl, swz);
    hidden<wact(F,4), wact(F,5)>(wt + (size_t)seg_off(F,5) * 512, bs + 4*HID, lnw + 5*HID, lnb + 5*HID, act, stats, w, lane, h, sl, swz);
    hidden<wact(F,5), wact(F,6)>(wt + (size_t)seg_off(F,6) * 512, bs + 5*HID, lnw + 6*HID, lnb + 6*HID, act, stats, w, lane, h, sl, swz);
    layer_out<wact(F,6)>(wt + (size_t)seg_off(F,7) * 512, b_out, act, out, F, samp0, w, lane, h, sl, swz);
}

__global__ __launch_bounds__(NW * 64, 2) void mipnet_kernel(
        const float* __restrict__ inp, const float* __restrict__ b_in,
        const float* __restrict__ bs, const float* __restrict__ lnw,
        const float* __restrict__ lnb, const float* __restrict__ b_out,
        const u16* __restrict__ wt, float* __restrict__ out) {
    extern __shared__ char lds[];
    char* act   = lds;
    char* stats = lds + STATS_OFF;
    const int tid  = threadIdx.x;
    const int w    = tid >> 6;
    const int lane = tid & 63;
    const int h    = lane >> 5;
    const int sl   = lane & 31;
    const int swz  = (sl & 15) << 4;     // XOR bits 4-7 (16B granule), bijective per sample row
    const int samp0 = blockIdx.x * BSAMP;

    // input B-fragments, built once, reused by all 3 factors (K = 6 padded to 16)
    f16x8 ib[ST];
    #pragma unroll
    for (int st = 0; st < ST; ++st) {
        f16x8 B = {(f16)0.f,(f16)0.f,(f16)0.f,(f16)0.f,(f16)0.f,(f16)0.f,(f16)0.f,(f16)0.f};
        if (h == 0) {
            const float* p = inp + (size_t)(samp0 + st * 32 + sl) * 6;
            float2 v0 = *reinterpret_cast<const float2*>(p + 0);
            float2 v1 = *reinterpret_cast<const float2*>(p + 2);
            float2 v2 = *reinterpret_cast<const float2*>(p + 4);
            B[0] = (f16)v0.x; B[1] = (f16)v0.y;
            B[2] = (f16)v1.x; B[3] = (f16)v1.y;
            B[4] = (f16)v2.x; B[5] = (f16)v2.y;
        }
        ib[st] = B;
    }
    run_factor<0>(b_in, bs, lnw, lnb, b_out, wt, out, act, stats, ib, samp0, w, lane, h, sl, swz);
    run_factor<1>(b_in, bs, lnw, lnb, b_out, wt, out, act, stats, ib, samp0, w, lane, h, sl, swz);
    run_factor<2>(b_in, bs, lnw, lnb, b_out, wt, out, act, stats, ib, samp0, w, lane, h, sl, swz);
}

extern "C" void kernel_launch(void* const* d_in, const int* in_sizes, int n_in,
                              void* d_out, int out_size, void* d_ws, size_t ws_size,
                              hipStream_t stream) {
    (void)in_sizes; (void)n_in; (void)out_size; (void)ws_size;
    const float* inputs = (const float*)d_in[0];
    const float* W_in   = (const float*)d_in[1];
    const float* b_in   = (const float*)d_in[2];
    const float* Ws     = (const float*)d_in[3];
    const float* bs     = (const float*)d_in[4];
    const float* lnw    = (const float*)d_in[5];
    const float* lnb    = (const float*)d_in[6];
    const float* W_out  = (const float*)d_in[7];
    const float* b_out  = (const float*)d_in[8];
    u16* wt = (u16*)d_ws;   // TOTAL_TILES*1024 = ~5.5MB of scratch

    hipFuncSetAttribute(reinterpret_cast<const void*>(mipnet_kernel),
                        hipFuncAttributeMaxDynamicSharedMemorySize, LDS_TOTAL);

    prep_kernel<<<TOTAL_TILES, 256, 0, stream>>>(W_in, Ws, W_out, wt);
    mipnet_kernel<<<NSAMP / BSAMP, NW * 64, LDS_TOTAL, stream>>>(
        inputs, b_in, bs, lnw, lnb, b_out, wt, (float*)d_out);
}